// Round 1
// baseline (97.647 us; speedup 1.0000x reference)
//
#include <hip/hip_runtime.h>
#include <math.h>
#include <float.h>
#include <stdint.h>

#define BIGINT_F 1e10f
#define L_TOK 128
#define C_ATOM 14
#define E_DIM 256
#define K_NB 9

// strict f32: ((x*x + y*y) + z*z), no FMA contraction (match np order)
__device__ __forceinline__ float sq3(float x, float y, float z) {
    return __fadd_rn(__fadd_rn(__fmul_rn(x, x), __fmul_rn(y, y)), __fmul_rn(z, z));
}

// Full-wave (64-lane) min reduction via DPP. Result valid in lane 63.
// min is idempotent, so all-lanes-enabled masks are safe; bound_ctrl=false
// keeps `old` (= own value) on invalid fetches = identity for min.
__device__ __forceinline__ float wave_min63(float v) {
#define DPP_MIN(ctrl)                                                         \
    v = fminf(v, __int_as_float(__builtin_amdgcn_update_dpp(                  \
            __float_as_int(v), __float_as_int(v), (ctrl), 0xf, 0xf, false)));
    DPP_MIN(0x111)   // row_shr:1
    DPP_MIN(0x112)   // row_shr:2
    DPP_MIN(0x114)   // row_shr:4
    DPP_MIN(0x118)   // row_shr:8  -> lane15/31/47/63 hold row mins
    DPP_MIN(0x142)   // row_bcast:15 -> lane31=min(r0,r1), lane63=min(r2,r3-ish)
    DPP_MIN(0x143)   // row_bcast:31 -> lane63 = full min
#undef DPP_MIN
    return v;
}

// One fused kernel. Block roles by blockIdx.x:
//   [0, NKNN)            : knn — 4 waves/block, one wave per row (b,i)
//   [NKNN, NKNN+N)       : embed — one block per token n
//   [NKNN+N, ...)        : adj — 256 elements per block
__global__ void __launch_bounds__(256)
fused_kernel(const int* __restrict__ S, const int* __restrict__ RP,
             const int* __restrict__ A, const int* __restrict__ AP,
             const float* __restrict__ X, const int* __restrict__ seg,
             const float* __restrict__ res_embed,
             const float* __restrict__ atom_embed,
             const float* __restrict__ atom_pos_embed,
             float* __restrict__ h,
             float* __restrict__ ctx_src, float* __restrict__ ctx_dst, float* __restrict__ ctx_val,
             float* __restrict__ adj_out,
             float* __restrict__ int_src, float* __restrict__ int_dst, float* __restrict__ int_val,
             int N) {
    const int NKNN = N / 4;          // 4 rows per block (one per wave)
    int blk = blockIdx.x;
    int tid = threadIdx.x;

    if (blk < NKNN) {
        // ----------------- KNN: wave-per-row -----------------
        int wave = tid >> 6;
        int lane = tid & 63;
        int bi = blk * 4 + wave;             // b*L + i
        int b  = bi >> 7;
        int i  = bi & (L_TOK - 1);
        const float INF_F = __int_as_float(0x7f800000);

        // Stage row-i atoms. Store za = -2*x (exact scaling) so the inner loop
        // computes t = (-2x0)y0 + (-2x1)y1 + (-2x2)y2, which is bit-identical
        // to -(2*dot) under RN (pow2 scaling commutes with rounding), and
        // d2 = (sa+sc) + t  ==  (sa+sc) - 2*dot  bitwise.
        __shared__ float4 sxi[4][C_ATOM];
        if (lane < C_ATOM) {
            const float* xp = X + ((size_t)bi * C_ATOM + lane) * 3;
            float x0 = xp[0], x1 = xp[1], x2 = xp[2];
            float sq = (AP[bi * C_ATOM + lane] == 0) ? INF_F : sq3(x0, x1, x2);
            sxi[wave][lane] = make_float4(__fmul_rn(x0, -2.0f),
                                          __fmul_rn(x1, -2.0f),
                                          __fmul_rn(x2, -2.0f), sq);
        }
        __syncthreads();   // block-uniform path: safe

        float za0[C_ATOM], za1[C_ATOM], za2[C_ATOM], sa[C_ATOM];
        #pragma unroll
        for (int a = 0; a < C_ATOM; ++a) {
            float4 t = sxi[wave][a];
            za0[a] = t.x; za1[a] = t.y; za2[a] = t.z; sa[a] = t.w;
        }

        int j0 = lane, j1 = lane + 64;
        int nj0 = (b << 7) + j0, nj1 = (b << 7) + j1;

        float mind0 = INF_F, mind1 = INF_F;
        for (int c = 0; c < C_ATOM; ++c) {
            const float* yp0 = X + ((size_t)nj0 * C_ATOM + c) * 3;
            const float* yp1 = X + ((size_t)nj1 * C_ATOM + c) * 3;
            float y00 = yp0[0], y01 = yp0[1], y02 = yp0[2];
            float y10 = yp1[0], y11 = yp1[1], y12 = yp1[2];
            float sc0 = (AP[nj0 * C_ATOM + c] == 0) ? INF_F : sq3(y00, y01, y02);
            float sc1 = (AP[nj1 * C_ATOM + c] == 0) ? INF_F : sq3(y10, y11, y12);
            #pragma unroll
            for (int a = 0; a < C_ATOM; ++a) {
                float t0 = __fadd_rn(__fadd_rn(__fmul_rn(za0[a], y00),
                                               __fmul_rn(za1[a], y01)),
                                     __fmul_rn(za2[a], y02));
                mind0 = fminf(mind0, __fadd_rn(__fadd_rn(sa[a], sc0), t0));
                float t1 = __fadd_rn(__fadd_rn(__fmul_rn(za0[a], y10),
                                               __fmul_rn(za1[a], y11)),
                                     __fmul_rn(za2[a], y12));
                mind1 = fminf(mind1, __fadd_rn(__fadd_rn(sa[a], sc1), t1));
            }
        }
        float d0 = sqrtf(fmaxf(mind0, 0.0f));
        float d1 = sqrtf(fmaxf(mind1, 0.0f));

        int si = S[bi];
        int segi = seg[bi];
        bool gi = si >= 21;
        int sj0 = S[nj0], sj1 = S[nj1];
        int segj0 = seg[nj0], segj1 = seg[nj1];
        bool gj0 = sj0 >= 21, gj1 = sj1 >= 21;
        bool ng0 = !gi && !gj0 && (j0 != i);
        bool ng1 = !gi && !gj1 && (j1 != i);
        bool inner0 = (segi == segj0) && ng0;
        bool inner1 = (segi == segj1) && ng1;
        bool outer0 = (segi != segj0) && ng0;
        bool outer1 = (segi != segj1) && ng1;

        // Candidates: masked-out = +INF (reference uses BIGINT for masked;
        // validity below is strict d < BIGINT so INF is equivalent).
        float cA0 = inner0 ? d0 : INF_F;   // pass A = ctx (inner), j = lane
        float cA1 = inner1 ? d1 : INF_F;   //                      j = lane+64
        float cB0 = outer0 ? d0 : INF_F;   // pass B = inter (outer)
        float cB1 = outer1 ? d1 : INF_F;

        float rsA = -1.0f, rdA = -1.0f, rvA = 0.0f;
        float rsB = -1.0f, rdB = -1.0f, rvB = 0.0f;

        // 9 extractions, both passes interleaved (independent DPP chains
        // overlap). Tie-break: min d, then min j — c0 set (j<64) checked
        // first, then lowest lane = lowest j. Matches stable top_k.
        #pragma unroll
        for (int k = 0; k < K_NB; ++k) {
            float mA = wave_min63(fminf(cA0, cA1));
            float mB = wave_min63(fminf(cB0, cB1));
            float sAv = __int_as_float(__builtin_amdgcn_readlane(__float_as_int(mA), 63));
            float sBv = __int_as_float(__builtin_amdgcn_readlane(__float_as_int(mB), 63));

            // ---- pass A owner + clear (ballots are wave-uniform branches) ----
            int jA;
            unsigned long long ba0 = __ballot(cA0 == sAv);
            if (ba0) {
                int l = __builtin_ctzll(ba0);
                jA = l;
                if (lane == l) cA0 = INF_F;
            } else {
                unsigned long long ba1 = __ballot(cA1 == sAv);
                int l = __builtin_ctzll(ba1);
                jA = l + 64;
                if (lane == l) cA1 = INF_F;
            }
            // ---- pass B owner + clear ----
            int jB;
            unsigned long long bb0 = __ballot(cB0 == sBv);
            if (bb0) {
                int l = __builtin_ctzll(bb0);
                jB = l;
                if (lane == l) cB0 = INF_F;
            } else {
                unsigned long long bb1 = __ballot(cB1 == sBv);
                int l = __builtin_ctzll(bb1);
                jB = l + 64;
                if (lane == l) cB1 = INF_F;
            }

            // lane k keeps result k (no runtime array indexing -> stays in regs)
            if (lane == k) {
                bool okA = sAv < BIGINT_F;
                rsA = okA ? (float)bi : -1.0f;
                rdA = okA ? (float)((b << 7) + jA) : -1.0f;
                rvA = okA ? 1.0f : 0.0f;
                bool okB = sBv < BIGINT_F;
                rsB = okB ? (float)bi : -1.0f;
                rdB = okB ? (float)((b << 7) + jB) : -1.0f;
                rvB = okB ? 1.0f : 0.0f;
            }
        }

        // coalesced result writes: lanes 0..8 write contiguous entries
        if (lane < K_NB) {
            int o = bi * K_NB + lane;
            ctx_src[o] = rsA; ctx_dst[o] = rdA; ctx_val[o] = rvA;
            int_src[o] = rsB; int_dst[o] = rdB; int_val[o] = rvB;
        }
    } else if (blk < NKNN + N) {
        // ----------------- EMBED: one block per token -----------------
        int n = blk - NKNN;
        int e = tid;  // 0..255
        int s = S[n];
        float rp = (float)RP[n];

        int k = e >> 1;
        // 10000^(-2k/E) = exp2(k * (-2*log2(10000)/E))
        const float c1 = (float)(-2.0 * 13.287712379549449 / (double)E_DIM);
        float invk = exp2f((float)k * c1);
        float ang = rp * invk;
        float pe = (e & 1) ? cosf(ang) : sinf(ang);
        h[(size_t)n * (2 * E_DIM) + e] = res_embed[s * E_DIM + e] + pe;

        __shared__ int sA[C_ATOM], sAP[C_ATOM];
        if (e < C_ATOM) { sA[e] = A[n * C_ATOM + e]; sAP[e] = AP[n * C_ATOM + e]; }
        __syncthreads();

        float sum = 0.0f, cnt = 0.0f;
        for (int c = 0; c < C_ATOM; ++c) {
            if (sAP[c] != 0) {
                sum += atom_embed[sA[c] * E_DIM + e] + atom_pos_embed[sAP[c] * E_DIM + e];
                cnt += 1.0f;
            }
        }
        h[(size_t)n * (2 * E_DIM) + E_DIM + e] = sum / (cnt + 1e-10f);
    } else {
        // ----------------- ADJ -----------------
        int idx = (blk - NKNN - N) * 256 + tid;   // over B*L*L
        int b = idx >> 14;
        int i = (idx >> 7) & (L_TOK - 1);
        int j = idx & (L_TOK - 1);
        int ni = (b << 7) + i, nj = (b << 7) + j;
        bool gi = S[ni] >= 21, gj = S[nj] >= 21;
        int segi = seg[ni], segj = seg[nj];
        bool notself = (i != j);
        bool same = (segi == segj);
        bool gn = same && (gi || gj) && notself;
        bool gg = gi && gj && notself;
        int d = i - j;
        bool adjacent = (d == 1 || d == -1);
        bool sm = adjacent && !(gi || gj) && (segi != 1);  // AG_SEG=1
        adj_out[idx] = (gn || gg || sm) ? 1.0f : 0.0f;
    }
}

extern "C" void kernel_launch(void* const* d_in, const int* in_sizes, int n_in,
                              void* d_out, int out_size, void* d_ws, size_t ws_size,
                              hipStream_t stream) {
    const int*   S    = (const int*)d_in[0];
    const int*   RP   = (const int*)d_in[1];
    const int*   A    = (const int*)d_in[2];
    const int*   AP   = (const int*)d_in[3];
    const float* X    = (const float*)d_in[4];
    const int*   seg  = (const int*)d_in[5];
    const float* rese = (const float*)d_in[6];
    const float* atme = (const float*)d_in[7];
    const float* atpe = (const float*)d_in[8];

    const int N = in_sizes[0];       // 2048
    const int B = N / L_TOK;         // 16
    float* out = (float*)d_out;

    size_t off = 0;
    float* h_out   = out + off;  off += (size_t)N * 2 * E_DIM;
    float* ctx_src = out + off;  off += (size_t)N * K_NB;
    float* ctx_dst = out + off;  off += (size_t)N * K_NB;
    float* ctx_val = out + off;  off += (size_t)N * K_NB;
    float* adj_out = out + off;  off += (size_t)B * L_TOK * L_TOK;
    float* int_src = out + off;  off += (size_t)N * K_NB;
    float* int_dst = out + off;  off += (size_t)N * K_NB;
    float* int_val = out + off;  off += (size_t)N * K_NB;

    int nknn = N / 4;                          // 512
    int nadj = (B * L_TOK * L_TOK) / 256;      // 1024
    int grid = nknn + N + nadj;                // 3584
    fused_kernel<<<grid, 256, 0, stream>>>(S, RP, A, AP, X, seg, rese, atme, atpe,
                                           h_out, ctx_src, ctx_dst, ctx_val,
                                           adj_out, int_src, int_dst, int_val, N);
}